// Round 6
// baseline (12122.193 us; speedup 1.0000x reference)
//
#include <hip/hip_runtime.h>
#include <stdint.h>
#include <stddef.h>

// Problem constants
#define Bn 32
#define Tn 1024
#define In 512
#define Hn 1024
#define NBLK 32    // LSTM roles; role owns 32 h-cols (128 gate rows)
#define NGRID 256  // launch 256 blocks; 32 on ONE elected XCD run, rest exit
#define NTHR 256   // 4 waves, 1 wave/SIMD -> 512-reg unified budget
#define GP 132     // gbuf pitch (pad to break 128-float bank alias)

typedef _Float16 half8 __attribute__((ext_vector_type(8)));
typedef float float4x __attribute__((ext_vector_type(4)));
#define MFMA(a, b, c) __builtin_amdgcn_mfma_f32_16x16x32_f16((a), (b), (c), 0, 0, 0)

// ---------------------------------------------------------------------------
// v7: single-XCD execution -> cross-block comm via XCD-local L2 (sc0), not LLC.
// v6 post-mortem: clock boost neutral; spinner duty cycle (~28% VALU at a
// 1024-cy FMA burst per poll) exposed agent-scope (sc0+sc1, LLC) load RT of
// ~2-2.5k cycles. The step's serial chain is ~3.5 such RTs -> that IS the
// step time. Fix: elect one XCD, run all 32 LSTM blocks there, use sc0-only
// (L1-bypass, L2-coherent) inline-asm ops for h staging / h write-through /
// flag publish / poll. L2 RT ~250 cy vs LLC ~2k.
//
// Election protocol (hang-free): each block reads HW_REG_XCC_ID, claims
// slot = atomicAdd(ctr[xcd]). Claimants wait for election (capped spin).
// The 32nd claimant on an XCD CASes elect=xcd+1 (first wins). Blocks with
// elect==their xcd && slot<32 run role nb=slot; all others exit. Pigeonhole:
// 256 blocks / 8 XCDs, claimants never exit pre-election, 82KB LDS forces
// 1 block/CU -> some XCD must reach 32 co-resident claimants -> election
// always resolves. All spins capped -> worst case visible FAIL, never hang.
//
// Coherence: CDNA vector L1 is write-through; sc0 ops bypass L1 and are
// served by the XCD's L2, which is shared/coherent for its 32 CUs. All
// participants are on one XCD -> sc0 suffices. Cross-kernel visibility of
// prep_w/prep_x/memset data is handled by launch-boundary acquire/release.
// Explicit s_waitcnt vmcnt(0) before the drain barrier (compiler can't see
// asm stores) and sched_barrier(0) after asm-load waits (rule #18).
//
// Workspace:
//   Wp    : 12.58 MB; bias: 16 KB; xp: 33.55 MB
//   hp    : 2 buf * 2 mt * 32 kc * 512 = 65,536 halves (128 KB), A-frag layout
//   flags : 32*16 ints seq flags, then ctr[8], elect  (memset each launch)
// ---------------------------------------------------------------------------

__global__ void prep_w_k(const float* __restrict__ Wih, const float* __restrict__ Whh,
                         const float* __restrict__ bih, const float* __restrict__ bhh,
                         _Float16* __restrict__ Wp, float* __restrict__ bias) {
  int nb = blockIdx.x;
  for (int p = threadIdx.x; p < 8 * 48 * 64; p += blockDim.x) {
    int nt = p / (48 * 64);
    int rem = p % (48 * 64);
    int kc = rem >> 6, lane = rem & 63;
    int row = ((nt >> 1) << 10) + (nb << 5) + ((nt & 1) << 4) + (lane & 15);
    int kb = (kc << 5) + ((lane >> 4) << 3);
    half8 v;
#pragma unroll
    for (int j = 0; j < 8; ++j) {
      int k = kb + j;
      float w = (k < In) ? Wih[(size_t)row * In + k] : Whh[(size_t)row * Hn + (k - In)];
      v[j] = (_Float16)w;
    }
    *(half8*)(Wp + (((size_t)nb * 8 + nt) * 48 + kc) * 512 + lane * 8) = v;
  }
  if (threadIdx.x < 128) {
    int nt = threadIdx.x >> 4, r = threadIdx.x & 15;
    int row = ((nt >> 1) << 10) + (nb << 5) + ((nt & 1) << 4) + r;
    bias[nb * 128 + threadIdx.x] = bih[row] + bhh[row];
  }
}

__global__ void prep_x_k(const float* __restrict__ x, _Float16* __restrict__ xp) {
  int t = blockIdx.x;
  for (int p = threadIdx.x; p < 2048; p += blockDim.x) {
    int mt = p >> 10, rem = p & 1023, kc = rem >> 6, lane = rem & 63;
    int b = (lane & 15) + (mt << 4);
    int k = (kc << 5) + ((lane >> 4) << 3);
    const float* src = x + ((size_t)b * Tn + t) * In + k;
    half8 v;
#pragma unroll
    for (int j = 0; j < 8; ++j) v[j] = (_Float16)src[j];
    *(half8*)(xp + ((size_t)(t * 2 + mt) * 16 + kc) * 512 + lane * 8) = v;
  }
}

__global__ __launch_bounds__(NTHR, 1) void lstm_k(
    const _Float16* __restrict__ xp, const _Float16* __restrict__ Wp,
    const float* __restrict__ bias, _Float16* __restrict__ hp,
    int* __restrict__ flags, float* __restrict__ out) {
  __shared__ __attribute__((aligned(16))) _Float16 hs[2 * 32 * 512];  // 64 KB
  __shared__ float gbuf[32 * GP];                                     // 16.9 KB
  __shared__ int s_slot;

  const int tid = threadIdx.x;
  const int wave = tid >> 6, lane = tid & 63;

  // ---- XCD election: decide whether this block is one of the 32 workers ----
  {
    unsigned xcc;
    asm volatile("s_getreg_b32 %0, hwreg(HW_REG_XCC_ID)" : "=s"(xcc));
    xcc &= 7;
    if (tid == 0) {
      int* ctr = flags + 512;   // ctr[8]
      int* elect = flags + 520; // election var: 0 = undecided, else xcd+1
      int slot = atomicAdd(&ctr[xcc], 1);
      if (slot == NBLK - 1) atomicCAS(elect, 0, (int)xcc + 1);
      int e = 0;
      for (long i = 0; i < 200000000L; ++i) {  // capped: never hangs
        e = __hip_atomic_load(elect, __ATOMIC_RELAXED, __HIP_MEMORY_SCOPE_AGENT);
        if (e != 0) break;
        __builtin_amdgcn_s_sleep(8);
      }
      s_slot = (e == (int)xcc + 1 && slot < NBLK) ? slot : -1;
    }
  }
  __syncthreads();
  const int nb = s_slot;
  if (nb < 0) return;  // not elected: free the CU immediately

  // wave owns gate-tiles nt0 = wave, nt1 = wave+4
  const int nt0 = wave, nt1 = wave + 4;
  const int g0 = nt0 >> 1, h0_ = nt0 & 1;
  const int g1 = nt1 >> 1, h1_ = nt1 & 1;

  // ---- W resident in registers (unified VGPR/AGPR) for the whole sequence ----
  half8 wx0[16], wx1[16], wh0[32], wh1[32];
  {
    const _Float16* b0 = Wp + ((size_t)nb * 8 + nt0) * 48 * 512;
    const _Float16* b1 = Wp + ((size_t)nb * 8 + nt1) * 48 * 512;
#pragma unroll
    for (int kc = 0; kc < 16; ++kc) {
      wx0[kc] = *(const half8*)(b0 + (size_t)kc * 512 + lane * 8);
      wx1[kc] = *(const half8*)(b1 + (size_t)kc * 512 + lane * 8);
    }
#pragma unroll
    for (int kc = 0; kc < 32; ++kc) {
      wh0[kc] = *(const half8*)(b0 + (size_t)(16 + kc) * 512 + lane * 8);
      wh1[kc] = *(const half8*)(b1 + (size_t)(16 + kc) * 512 + lane * 8);
    }
  }
#pragma unroll
  for (int i = 0; i < 16; ++i) {
    asm volatile("" : "+v"(wx0[i]));
    asm volatile("" : "+v"(wx1[i]));
  }
#pragma unroll
  for (int i = 0; i < 32; ++i) {
    asm volatile("" : "+v"(wh0[i]));
    asm volatile("" : "+v"(wh1[i]));
  }
  const float bv0 = bias[nb * 128 + nt0 * 16 + (lane & 15)];
  const float bv1 = bias[nb * 128 + nt1 * 16 + (lane & 15)];

  // pointwise identity: batch pb = tid>>3, cols 4*pc .. 4*pc+3
  const int pb = tid >> 3, pc = tid & 7;
  float cr[4] = {0.f, 0.f, 0.f, 0.f};

  // ---- prologue: x-part of step 0 ----
  float4x a00 = {0.f, 0.f, 0.f, 0.f}, a01 = {0.f, 0.f, 0.f, 0.f};
  float4x a10 = {0.f, 0.f, 0.f, 0.f}, a11 = {0.f, 0.f, 0.f, 0.f};
  {
    const _Float16* xb = xp;  // t = 0
#pragma unroll
    for (int kc = 0; kc < 16; ++kc) {
      half8 x0 = *(const half8*)(xb + (size_t)kc * 512 + lane * 8);
      half8 x1 = *(const half8*)(xb + (size_t)(16 + kc) * 512 + lane * 8);
      a00 = MFMA(x0, wx0[kc], a00);
      a01 = MFMA(x0, wx1[kc], a01);
      a10 = MFMA(x1, wx0[kc], a10);
      a11 = MFMA(x1, wx1[kc], a11);
    }
  }

  for (int t = 0; t < Tn; ++t) {
    const int cur = t & 1;

    // ---- stage h_t: 64 KB hp[cur] -> LDS via sc0 loads (XCD-L2 coherent,
    // L1 bypass). 32 loads in flight, one wait, then LDS writes. ----
    {
      const uint64_t sbase = (uint64_t)(hp + (size_t)cur * 32768);
      const unsigned voff0 = (unsigned)(tid * 8);
      unsigned long long tmp[32];
#pragma unroll
      for (int i = 0; i < 32; ++i)
        asm volatile("global_load_dwordx2 %0, %1, %2 sc0"
                     : "=&v"(tmp[i]) : "v"(voff0 + i * 2048u), "s"(sbase));
      asm volatile("s_waitcnt vmcnt(0)" ::: "memory");
      __builtin_amdgcn_sched_barrier(0);
      unsigned long long* hdst = (unsigned long long*)hs;
#pragma unroll
      for (int i = 0; i < 32; ++i) hdst[tid + i * 256] = tmp[i];
    }
    __syncthreads();

    // ---- h-part MFMA: 32 K-chunks x 2 mt x 2 nt-tiles, W from registers ----
#pragma unroll
    for (int kc = 0; kc < 32; ++kc) {
      half8 ha0 = *(const half8*)(hs + (size_t)kc * 512 + lane * 8);
      half8 ha1 = *(const half8*)(hs + (size_t)(32 + kc) * 512 + lane * 8);
      a00 = MFMA(ha0, wh0[kc], a00);
      a01 = MFMA(ha0, wh1[kc], a01);
      a10 = MFMA(ha1, wh0[kc], a10);
      a11 = MFMA(ha1, wh1[kc], a11);
    }

    // ---- gates to LDS ----
    {
      const int r0 = (lane >> 4) * 4;
      const int c0 = g0 * 32 + h0_ * 16 + (lane & 15);
      const int c1 = g1 * 32 + h1_ * 16 + (lane & 15);
#pragma unroll
      for (int r = 0; r < 4; ++r) {
        gbuf[(r0 + r) * GP + c0] = a00[r] + bv0;
        gbuf[(r0 + r) * GP + c1] = a01[r] + bv1;
        gbuf[(16 + r0 + r) * GP + c0] = a10[r] + bv0;
        gbuf[(16 + r0 + r) * GP + c1] = a11[r] + bv1;
      }
    }
    __syncthreads();

    // ---- pointwise LSTM cell: all 256 threads, 4 cols each ----
    {
      const int col = pc * 4;
      const float* gr = gbuf + pb * GP;
      float hv[4];
#pragma unroll
      for (int c = 0; c < 4; ++c) {
        float gi = gr[col + c], gf = gr[32 + col + c];
        float gg = gr[64 + col + c], go = gr[96 + col + c];
        float i_ = 1.f / (1.f + __expf(-gi));
        float f_ = 1.f / (1.f + __expf(-gf));
        float g_ = 1.f - 2.f / (1.f + __expf(2.f * gg));
        float o_ = 1.f / (1.f + __expf(-go));
        cr[c] = f_ * cr[c] + i_ * g_;
        hv[c] = o_ * (1.f - 2.f / (1.f + __expf(2.f * cr[c])));
      }

      size_t ob = ((size_t)pb * Tn + t) * Hn + nb * 32 + col;
      float4x ov = {hv[0], hv[1], hv[2], hv[3]};
      *(float4x*)(out + ob) = ov;

      // h -> hp[next] in A-frag layout, write-through to XCD L2 (sc0)
      union { _Float16 h[4]; unsigned long long u; } pk;
#pragma unroll
      for (int c = 0; c < 4; ++c) pk.h[c] = (_Float16)hv[c];
      const int mtp = pb >> 4;
      const int lanep = (pb & 15) + (((col >> 3) & 3) << 4);
      size_t hoff = ((size_t)((cur ^ 1) * 2 + mtp) * 32 + nb) * 512 + lanep * 8 + (col & 7);
      asm volatile("global_store_dwordx2 %0, %1, off sc0"
                   :: "v"((uint64_t)(hp + hoff)), "v"(pk.u) : "memory");

      if (t == Tn - 1) {
        size_t base = (size_t)Bn * Tn * Hn;
        float4x cv = {cr[0], cr[1], cr[2], cr[3]};
        *(float4x*)(out + base + (size_t)pb * Hn + nb * 32 + col) = ov;                     // h_T
        *(float4x*)(out + base + (size_t)Bn * Hn + (size_t)pb * Hn + nb * 32 + col) = cv;  // c_T
      }
    }

    // drain: explicit (compiler can't see the asm h-stores), then barrier.
    asm volatile("s_waitcnt vmcnt(0)" ::: "memory");
    __syncthreads();

    // ---- publish FIRST: sc0 store to this block's seq flag (L2-local) ----
    if (tid == 0)
      asm volatile("global_store_dword %0, %1, off sc0"
                   :: "v"((uint64_t)(flags + nb * 16)), "v"(t + 1) : "memory");

    // ---- x-part MFMA for t+1 (no h dependency): inside the poll window ----
    {
      a00 = (float4x){0.f, 0.f, 0.f, 0.f};
      a01 = (float4x){0.f, 0.f, 0.f, 0.f};
      a10 = (float4x){0.f, 0.f, 0.f, 0.f};
      a11 = (float4x){0.f, 0.f, 0.f, 0.f};
      const int tn = (t + 1 < Tn) ? t + 1 : t;
      const _Float16* xb = xp + (size_t)tn * 2 * 16 * 512;
#pragma unroll
      for (int kc = 0; kc < 16; ++kc) {
        half8 x0 = *(const half8*)(xb + (size_t)kc * 512 + lane * 8);
        half8 x1 = *(const half8*)(xb + (size_t)(16 + kc) * 512 + lane * 8);
        a00 = MFMA(x0, wx0[kc], a00);
        a01 = MFMA(x0, wx1[kc], a01);
        a10 = MFMA(x1, wx0[kc], a10);
        a11 = MFMA(x1, wx1[kc], a11);
      }
    }

    // ---- grid barrier across the 32 workers: wave0 polls all seqs via sc0
    // (lanes 32-63 mirror 0-31: uniform, no divergence) ----
    if (wave == 0) {
      const int tgt = t + 1;
      const uint64_t pa = (uint64_t)(flags + (lane & (NBLK - 1)) * 16);
      for (int it = 0; it < 30000000; ++it) {  // capped: never hangs
        int v;
        asm volatile("global_load_dword %0, %1, off sc0\n\ts_waitcnt vmcnt(0)"
                     : "=v"(v) : "v"(pa) : "memory");
        if (__all(v >= tgt)) break;
        __builtin_amdgcn_s_sleep(1);
      }
    }
    __syncthreads();
  }
}

extern "C" void kernel_launch(void* const* d_in, const int* in_sizes, int n_in,
                              void* d_out, int out_size, void* d_ws, size_t ws_size,
                              hipStream_t stream) {
  const float* x   = (const float*)d_in[0];
  const float* Wih = (const float*)d_in[1];
  const float* Whh = (const float*)d_in[2];
  const float* bih = (const float*)d_in[3];
  const float* bhh = (const float*)d_in[4];
  float* out = (float*)d_out;

  char* ws = (char*)d_ws;
  _Float16* Wp   = (_Float16*)ws;                                  // 6,291,456 halves
  float*    bias = (float*)(ws + (size_t)6291456 * 2);             // 4096 floats
  _Float16* xp   = (_Float16*)(ws + (size_t)6291456 * 2 + 16384);  // 16,777,216 halves
  _Float16* hp   = xp + (size_t)16777216;                          // 65,536 halves
  int*      flags = (int*)(hp + 65536);                            // 512 seq + 8 ctr + elect

  prep_w_k<<<NBLK, 256, 0, stream>>>(Wih, Whh, bih, bhh, Wp, bias);
  prep_x_k<<<Tn, 256, 0, stream>>>(x, xp);
  hipMemsetAsync(hp, 0, 32768 * sizeof(_Float16), stream);       // zero h buffer 0
  hipMemsetAsync(flags, 0, (512 + 16) * sizeof(int), stream);    // seqs + ctrs + elect
  lstm_k<<<NGRID, NTHR, 0, stream>>>(xp, Wp, bias, hp, flags, out);
}